// Round 1
// baseline (27.154 us; speedup 1.0000x reference)
//
#include <hip/hip_runtime.h>

#define TILE 256
#define DELTA 10.0f

// Kernel A: each block computes partial sums over a TILE x TILE (i,j) tile.
__global__ void __launch_bounds__(TILE)
rank_pairs_kernel(const float* __restrict__ pred,
                  const int* __restrict__ target,
                  int B, int nTiles,
                  float* __restrict__ loss_part,
                  unsigned int* __restrict__ t_part,
                  unsigned int* __restrict__ n_part) {
    __shared__ float pj[TILE];
    __shared__ float tj[TILE];
    __shared__ float sl[TILE];
    __shared__ unsigned int st[TILE];
    __shared__ unsigned int sn[TILE];

    const int tid = threadIdx.x;
    const int bi = blockIdx.x / nTiles;
    const int bj = blockIdx.x % nTiles;
    const int j0 = bj * TILE;
    const int jg = j0 + tid;

    // Stage j-tile in LDS.
    if (jg < B) {
        pj[tid] = pred[jg];
        tj[tid] = (float)target[jg];
    } else {
        pj[tid] = 0.0f;
        tj[tid] = 0.0f;  // never read: inner loop bounded by jCount
    }
    __syncthreads();

    float loss = 0.0f;
    unsigned int tc = 0;
    unsigned int nc = 0;

    const int i = bi * TILE + tid;
    if (i < B) {
        const float pi = pred[i];
        const float fti = (float)target[i];
        const int jCount = min(TILE, B - j0);
        #pragma unroll 8
        for (int jj = 0; jj < jCount; ++jj) {
            // sf in {-1, 0, +1}; dp = (pred[pos]-pred[neg]) when valid, 0 when sf==0
            const float sf = fti - tj[jj];
            const float dp = (pi - pj[jj]) * sf;
            // h = max(DELTA + dp, 0) when |sf|==1, exactly 0 when sf==0
            const float h = fmaxf(fmaf(fabsf(sf), DELTA, dp), 0.0f);
            loss = fmaf(h, h, loss);
            tc += (dp > 0.0f) ? 1u : 0u;   // sf==0 => dp==0 => not counted
            nc += (sf != 0.0f) ? 1u : 0u;
        }
    }

    // Deterministic block tree reduction.
    sl[tid] = loss;
    st[tid] = tc;
    sn[tid] = nc;
    __syncthreads();
    for (int s = TILE / 2; s > 0; s >>= 1) {
        if (tid < s) {
            sl[tid] += sl[tid + s];
            st[tid] += st[tid + s];
            sn[tid] += sn[tid + s];
        }
        __syncthreads();
    }
    if (tid == 0) {
        loss_part[blockIdx.x] = sl[0];
        t_part[blockIdx.x]    = st[0];
        n_part[blockIdx.x]    = sn[0];
    }
}

// Kernel B: deterministic final reduction of nb partials -> two scalars.
__global__ void __launch_bounds__(256)
rank_finalize_kernel(const float* __restrict__ loss_part,
                     const unsigned int* __restrict__ t_part,
                     const unsigned int* __restrict__ n_part,
                     int nb, float* __restrict__ out) {
    __shared__ float sl[256];
    __shared__ unsigned int st[256];
    __shared__ unsigned int sn[256];
    const int tid = threadIdx.x;
    float l = 0.0f;
    unsigned int t = 0, n = 0;
    for (int k = tid; k < nb; k += 256) {
        l += loss_part[k];
        t += t_part[k];
        n += n_part[k];
    }
    sl[tid] = l; st[tid] = t; sn[tid] = n;
    __syncthreads();
    for (int s = 128; s > 0; s >>= 1) {
        if (tid < s) {
            sl[tid] += sl[tid + s];
            st[tid] += st[tid + s];
            sn[tid] += sn[tid + s];
        }
        __syncthreads();
    }
    if (tid == 0) {
        const double N = (double)sn[0];
        out[0] = (float)((double)sl[0] / N);
        out[1] = (float)((double)st[0] / N);
    }
}

extern "C" void kernel_launch(void* const* d_in, const int* in_sizes, int n_in,
                              void* d_out, int out_size, void* d_ws, size_t ws_size,
                              hipStream_t stream) {
    const float* pred  = (const float*)d_in[0];
    const int* target  = (const int*)d_in[1];
    const int B = in_sizes[0];
    const int nTiles = (B + TILE - 1) / TILE;
    const int nb = nTiles * nTiles;

    float*        loss_part = (float*)d_ws;
    unsigned int* t_part    = (unsigned int*)(loss_part + nb);
    unsigned int* n_part    = t_part + nb;

    rank_pairs_kernel<<<nb, TILE, 0, stream>>>(pred, target, B, nTiles,
                                               loss_part, t_part, n_part);
    rank_finalize_kernel<<<1, 256, 0, stream>>>(loss_part, t_part, n_part, nb,
                                                (float*)d_out);
}